// Round 9
// baseline (530.326 us; speedup 1.0000x reference)
//
#include <hip/hip_runtime.h>

// ---------------------------------------------------------------------------
// GraphVAE (3x TransformerConv + LN/ReLU + mean-pool + classifier).
// Round 9: 2 waves per node in the fused node kernel (split-edge online
// softmax combine via LDS) to halve the serial per-edge latency chain;
// GEMM computes 2 matrices per block (halves Xb re-reads).
// ---------------------------------------------------------------------------

typedef short short8v __attribute__((ext_vector_type(8)));
typedef float f32x4 __attribute__((ext_vector_type(4)));

__device__ __forceinline__ unsigned pack_bf16_rne(float a, float b) {
    unsigned ua = __float_as_uint(a);
    ua += 0x7fffu + ((ua >> 16) & 1u);
    unsigned ub = __float_as_uint(b);
    ub += 0x7fffu + ((ub >> 16) & 1u);
    return (ua >> 16) | (ub & 0xffff0000u);
}

__device__ __forceinline__ unsigned short bf16_rne1(float a) {
    unsigned u = __float_as_uint(a);
    u += 0x7fffu + ((u >> 16) & 1u);
    return (unsigned short)(u >> 16);
}

__device__ __forceinline__ float blo(unsigned u) { return __uint_as_float(u << 16); }
__device__ __forceinline__ float bhi(unsigned u) { return __uint_as_float(u & 0xffff0000u); }

__global__ __launch_bounds__(256) void hist_kernel(const int* __restrict__ dst,
                                                   int* __restrict__ cnt, int E) {
    int e = blockIdx.x * 256 + threadIdx.x;
    if (e < E) atomicAdd(&cnt[dst[e]], 1);
}

// ---- parallel scan: per-block reduce -> single-block scan -> fill ----
__global__ __launch_bounds__(256) void blk_reduce_kernel(const int* __restrict__ cnt,
                                                         int* __restrict__ bsum, int n) {
    __shared__ int ws[4];
    const int i = blockIdx.x * 256 + threadIdx.x;
    const int lane = threadIdx.x & 63, wid = threadIdx.x >> 6;
    int v = (i < n) ? cnt[i] : 0;
#pragma unroll
    for (int off = 1; off < 64; off <<= 1) v += __shfl_xor(v, off);
    if (lane == 0) ws[wid] = v;
    __syncthreads();
    if (threadIdx.x == 0) bsum[blockIdx.x] = ws[0] + ws[1] + ws[2] + ws[3];
}

__global__ __launch_bounds__(1024) void blk_scan_kernel(int* __restrict__ bsum, int nb) {
    __shared__ int wls[16];
    const int tid = threadIdx.x, lane = tid & 63, wid = tid >> 6;
    int v = (tid < nb) ? bsum[tid] : 0;
    int sc = v;
#pragma unroll
    for (int off = 1; off < 64; off <<= 1) {
        int t = __shfl_up(sc, off);
        if (lane >= off) sc += t;
    }
    if (lane == 63) wls[wid] = sc;
    __syncthreads();
    if (tid == 0) {
        int run = 0;
        for (int w = 0; w < 16; ++w) { int t = wls[w]; wls[w] = run; run += t; }
    }
    __syncthreads();
    if (tid < nb) bsum[tid] = wls[wid] + sc - v;  // exclusive
}

__global__ __launch_bounds__(256) void rowptr_fill_kernel(const int* __restrict__ cnt,
                                                          const int* __restrict__ boff,
                                                          int* __restrict__ rowptr, int n) {
    __shared__ int wls[4];
    const int i = blockIdx.x * 256 + threadIdx.x;
    const int lane = threadIdx.x & 63, wid = threadIdx.x >> 6;
    int v = (i < n) ? cnt[i] : 0;
    int sc = v;
#pragma unroll
    for (int off = 1; off < 64; off <<= 1) {
        int t = __shfl_up(sc, off);
        if (lane >= off) sc += t;
    }
    if (lane == 63) wls[wid] = sc;
    __syncthreads();
    int add = boff[blockIdx.x];
    for (int w = 0; w < wid; ++w) add += wls[w];
    if (i < n) rowptr[i + 1] = sc + add;
    if (i == 0) rowptr[0] = 0;
}

__global__ __launch_bounds__(256) void fill_kernel(const int* __restrict__ src,
                                                   const int* __restrict__ dst,
                                                   const float* __restrict__ attr,
                                                   const int* __restrict__ rowptr,
                                                   int* __restrict__ tmp,
                                                   int* __restrict__ src_perm,
                                                   float* __restrict__ attr_perm,
                                                   int* __restrict__ eidp, int E) {
    int e = blockIdx.x * 256 + threadIdx.x;
    if (e < E) {
        int d = dst[e];
        int p = atomicAdd(&tmp[d], 1);
        int pos = rowptr[d] + p;
        src_perm[pos] = src[e];
        attr_perm[pos] = attr[e];
        eidp[pos] = e;
    }
}

__global__ __launch_bounds__(256) void cvt_bf16_kernel(const float* __restrict__ in,
                                                       unsigned* __restrict__ outp, int n32) {
    int i = blockIdx.x * 256 + threadIdx.x;
    if (i < n32) {
        float2 v = *(const float2*)&in[(size_t)i * 2];
        outp[i] = pack_bf16_rne(v.x, v.y);
    }
}

struct W12 { const float* p[12]; };
__global__ __launch_bounds__(256) void prepack_all_kernel(W12 ws, unsigned* __restrict__ wt) {
    const int m = blockIdx.y;
    const float* W = ws.p[m];
    int idx = blockIdx.x * 256 + threadIdx.x;
    int c = idx >> 6;
    int kp = idx & 63;
    wt[(size_t)m * 8192 + (size_t)c * 64 + kp] =
        pack_bf16_rne(W[(size_t)(2 * kp) * 128 + c], W[(size_t)(2 * kp + 1) * 128 + c]);
}

// ---------------------------------------------------------------------------
// MFMA GEMM, 2 matrices per block: y=0 -> {q f32, k bf16}; y=1 -> {v bf16, s f32}
// ---------------------------------------------------------------------------
__global__ __launch_bounds__(256) void gemm_mfma_kernel(
    const unsigned short* __restrict__ Xb, const unsigned short* __restrict__ wt,
    const float* __restrict__ bq, const float* __restrict__ bk,
    const float* __restrict__ bv, const float* __restrict__ bs,
    float* __restrict__ qo, unsigned short* __restrict__ ko,
    unsigned short* __restrict__ vo, float* __restrict__ so, int nrows) {
    const int lane = threadIdx.x & 63;
    const int w = threadIdx.x >> 6;
    const int pair = blockIdx.y;             // 0: q,k   1: v,s
    const int strip = blockIdx.x * 64 + w * 16;
    const int arow = strip + (lane & 15);
    const int arow_c = min(arow, nrows - 1);
    const int kblk = (lane >> 4) * 8;
    const unsigned short* WmA = wt + (size_t)(pair * 2) * 16384;      // q or v
    const unsigned short* WmB = wt + (size_t)(pair * 2 + 1) * 16384;  // k or s
    // pair0: matA=q(f32), matB=k(bf16); pair1: matA=v(bf16), matB=s(f32)
    const float* biasA = (pair == 0) ? bq : bv;
    const float* biasB = (pair == 0) ? bk : bs;

    f32x4 accA[8], accB[8];
#pragma unroll
    for (int f = 0; f < 8; ++f) {
        accA[f] = (f32x4){0.f, 0.f, 0.f, 0.f};
        accB[f] = (f32x4){0.f, 0.f, 0.f, 0.f};
    }

#pragma unroll
    for (int ks = 0; ks < 4; ++ks) {
        const int k0 = ks * 32 + kblk;
        const short8v a = *(const short8v*)&Xb[(size_t)arow_c * 128 + k0];
#pragma unroll
        for (int f = 0; f < 8; ++f) {
            const size_t boff = (size_t)(f * 16 + (lane & 15)) * 128 + k0;
            const short8v b0 = *(const short8v*)&WmA[boff];
            const short8v b1 = *(const short8v*)&WmB[boff];
            accA[f] = __builtin_amdgcn_mfma_f32_16x16x32_bf16(a, b0, accA[f], 0, 0, 0);
            accB[f] = __builtin_amdgcn_mfma_f32_16x16x32_bf16(a, b1, accB[f], 0, 0, 0);
        }
    }

    const int r0 = strip + (lane >> 4) * 4;
#pragma unroll
    for (int f = 0; f < 8; ++f) {
        const int col = f * 16 + (lane & 15);
        const float bA = biasA[col];
        const float bB = biasB[col];
#pragma unroll
        for (int r = 0; r < 4; ++r) {
            int row = r0 + r;
            if (row < nrows) {
                if (pair == 0) {
                    qo[(size_t)row * 128 + col] = accA[f][r] + bA;
                    ko[(size_t)row * 128 + col] = bf16_rne1(accB[f][r] + bB);
                } else {
                    vo[(size_t)row * 128 + col] = bf16_rne1(accA[f][r] + bA);
                    so[(size_t)row * 128 + col] = accB[f][r] + bB;
                }
            }
        }
    }
}

// ---------------------------------------------------------------------------
// Fused node kernel v3: 2 waves per node (4 waves/block = 2 nodes).
// Each wave handles a contiguous half of the node's edges; online-softmax
// combine across the wave pair via LDS. deg<=128 fast; deg>128 -> part0 runs
// the old 3-pass fallback. Epilogue (part0): skip (+be) + LN/ReLU.
// Lane layout: lane l owns dims (2l, 2l+1); head h = l>>4.
// ---------------------------------------------------------------------------
__global__ __launch_bounds__(256) void node_fused_kernel(
    const float* __restrict__ qb, const unsigned* __restrict__ kb,
    const unsigned* __restrict__ vb,
    const float* __restrict__ Wev, const float* __restrict__ bev,
    const int* __restrict__ rowptr, const int* __restrict__ src_perm,
    const float* __restrict__ attr_perm, const int* __restrict__ eidp,
    float* __restrict__ alpha_perm, float* __restrict__ alpha_out,
    const float* __restrict__ skip, float* __restrict__ zout,
    unsigned* __restrict__ hbout,
    const float* __restrict__ lng, const float* __restrict__ lnb,
    int do_ln, int n) {
    __shared__ float alds[4][64][4];
    __shared__ float cmb[4][8];
    __shared__ float accb[2][64][2];
    const int wid = threadIdx.x >> 6;
    const int part = wid & 1;
    const int nslot = wid >> 1;
    const int nodeRaw = blockIdx.x * 2 + nslot;
    const bool live = nodeRaw < n;
    const int node = live ? nodeRaw : (n - 1);
    const int lane = threadIdx.x & 63;
    const int start = rowptr[node], end = rowptr[node + 1];
    const int deg = end - start;
    const bool fast = (deg <= 128);
    const int h = lane >> 4;
    const float we0 = Wev[2 * lane], we1 = Wev[2 * lane + 1];
    const float be0 = bev[2 * lane], be1 = bev[2 * lane + 1];
    const float2 qv = *(const float2*)&qb[(size_t)node * 128 + 2 * lane];
    const float scale = 0.17677669529663687f;  // 1/sqrt(32)

    // this wave's edge chunk
    const int h0 = (deg + 1) >> 1;
    const int cstart = start + part * h0;
    const int cdeg = part ? (deg - h0) : h0;

    float acc0 = 0.f, acc1 = 0.f, sa = 0.f;
    float4 m_w = make_float4(-1e30f, -1e30f, -1e30f, -1e30f);
    float4 s_w = make_float4(0.f, 0.f, 0.f, 0.f);
    float4 evr = make_float4(0.f, 0.f, 0.f, 0.f);
    bool valid = false;
    int sj = 0;
    float aj = 0.f;

    if (live && deg > 0 && fast) {
        // per-head q.we, q.be
        float pw = qv.x * we0 + qv.y * we1;
        float pb = qv.x * be0 + qv.y * be1;
#pragma unroll
        for (int off = 1; off < 16; off <<= 1) {
            pw += __shfl_xor(pw, off);
            pb += __shfl_xor(pb, off);
        }
        valid = lane < cdeg;
        sj = valid ? src_perm[cstart + lane] : 0;
        aj = valid ? attr_perm[cstart + lane] : 0.f;

        // pass A: chunk logits -> alds[wid][t][h]
        int t = 0;
        for (; t + 3 < cdeg; t += 4) {
            const int s0 = __shfl(sj, t), s1 = __shfl(sj, t + 1);
            const int s2 = __shfl(sj, t + 2), s3 = __shfl(sj, t + 3);
            const float a0 = __shfl(aj, t), a1 = __shfl(aj, t + 1);
            const float a2 = __shfl(aj, t + 2), a3 = __shfl(aj, t + 3);
            const unsigned u0 = kb[(size_t)s0 * 64 + lane];
            const unsigned u1 = kb[(size_t)s1 * 64 + lane];
            const unsigned u2 = kb[(size_t)s2 * 64 + lane];
            const unsigned u3 = kb[(size_t)s3 * 64 + lane];
            float p0 = qv.x * blo(u0) + qv.y * bhi(u0);
            float p1 = qv.x * blo(u1) + qv.y * bhi(u1);
            float p2 = qv.x * blo(u2) + qv.y * bhi(u2);
            float p3 = qv.x * blo(u3) + qv.y * bhi(u3);
#pragma unroll
            for (int off = 1; off < 16; off <<= 1) {
                p0 += __shfl_xor(p0, off); p1 += __shfl_xor(p1, off);
                p2 += __shfl_xor(p2, off); p3 += __shfl_xor(p3, off);
            }
            if ((lane & 15) == 0) {
                alds[wid][t + 0][h] = (p0 + a0 * pw + pb) * scale;
                alds[wid][t + 1][h] = (p1 + a1 * pw + pb) * scale;
                alds[wid][t + 2][h] = (p2 + a2 * pw + pb) * scale;
                alds[wid][t + 3][h] = (p3 + a3 * pw + pb) * scale;
            }
        }
        for (; t < cdeg; ++t) {
            const int s0 = __shfl(sj, t);
            const float a0 = __shfl(aj, t);
            const unsigned u0 = kb[(size_t)s0 * 64 + lane];
            float p0 = qv.x * blo(u0) + qv.y * bhi(u0);
#pragma unroll
            for (int off = 1; off < 16; off <<= 1) p0 += __shfl_xor(p0, off);
            if ((lane & 15) == 0) alds[wid][t][h] = (p0 + a0 * pw + pb) * scale;
        }

        // local softmax stats
        float4 lg = valid ? *(const float4*)&alds[wid][lane][0]
                          : make_float4(-1e30f, -1e30f, -1e30f, -1e30f);
        float4 mx = lg;
#pragma unroll
        for (int off = 1; off < 64; off <<= 1) {
            mx.x = fmaxf(mx.x, __shfl_xor(mx.x, off));
            mx.y = fmaxf(mx.y, __shfl_xor(mx.y, off));
            mx.z = fmaxf(mx.z, __shfl_xor(mx.z, off));
            mx.w = fmaxf(mx.w, __shfl_xor(mx.w, off));
        }
        float4 ev;
        ev.x = __expf(lg.x - mx.x); ev.y = __expf(lg.y - mx.y);
        ev.z = __expf(lg.z - mx.z); ev.w = __expf(lg.w - mx.w);
        float4 s4 = ev;
#pragma unroll
        for (int off = 1; off < 64; off <<= 1) {
            s4.x += __shfl_xor(s4.x, off); s4.y += __shfl_xor(s4.y, off);
            s4.z += __shfl_xor(s4.z, off); s4.w += __shfl_xor(s4.w, off);
        }
        m_w = mx; s_w = s4; evr = ev;
    } else if (live && deg > 0 && !fast && part == 0) {
        // ---------------- fallback (deg > 128), single wave ----------------
        float mh = -1e30f;
        for (int c0 = start; c0 < end; c0 += 64) {
            const int nc = min(64, end - c0);
            const int sjf = (lane < nc) ? src_perm[c0 + lane] : 0;
            const float ajf = (lane < nc) ? attr_perm[c0 + lane] : 0.f;
            int t = 0;
            for (; t + 1 < nc; t += 2) {
                const int s0 = __shfl(sjf, t), s1 = __shfl(sjf, t + 1);
                const float a0 = __shfl(ajf, t), a1 = __shfl(ajf, t + 1);
                const unsigned u0 = kb[(size_t)s0 * 64 + lane];
                const unsigned u1 = kb[(size_t)s1 * 64 + lane];
                float p0 = qv.x * (blo(u0) + a0 * we0 + be0) + qv.y * (bhi(u0) + a0 * we1 + be1);
                float p1 = qv.x * (blo(u1) + a1 * we0 + be0) + qv.y * (bhi(u1) + a1 * we1 + be1);
#pragma unroll
                for (int off = 1; off < 16; off <<= 1) {
                    p0 += __shfl_xor(p0, off);
                    p1 += __shfl_xor(p1, off);
                }
                p0 *= scale; p1 *= scale;
                mh = fmaxf(mh, fmaxf(p0, p1));
                if ((lane & 15) == 0) {
                    alpha_perm[(size_t)(c0 + t) * 4 + h] = p0;
                    alpha_perm[(size_t)(c0 + t + 1) * 4 + h] = p1;
                }
            }
            if (t < nc) {
                const int s0 = __shfl(sjf, t);
                const float a0 = __shfl(ajf, t);
                const unsigned u0 = kb[(size_t)s0 * 64 + lane];
                float p0 = qv.x * (blo(u0) + a0 * we0 + be0) + qv.y * (bhi(u0) + a0 * we1 + be1);
#pragma unroll
                for (int off = 1; off < 16; off <<= 1) p0 += __shfl_xor(p0, off);
                p0 *= scale;
                mh = fmaxf(mh, p0);
                if ((lane & 15) == 0) alpha_perm[(size_t)(c0 + t) * 4 + h] = p0;
            }
        }
        const float m0 = __shfl(mh, 0), m1 = __shfl(mh, 16);
        const float m2 = __shfl(mh, 32), m3 = __shfl(mh, 48);

        float4 s4 = make_float4(0.f, 0.f, 0.f, 0.f);
        for (int c0 = start; c0 < end; c0 += 64) {
            const int j = c0 + lane;
            if (j < end) {
                float4 lg = *(const float4*)&alpha_perm[(size_t)j * 4];
                lg.x = __expf(lg.x - m0); lg.y = __expf(lg.y - m1);
                lg.z = __expf(lg.z - m2); lg.w = __expf(lg.w - m3);
                *(float4*)&alpha_perm[(size_t)j * 4] = lg;
                s4.x += lg.x; s4.y += lg.y; s4.z += lg.z; s4.w += lg.w;
            }
        }
#pragma unroll
        for (int off = 1; off < 64; off <<= 1) {
            s4.x += __shfl_xor(s4.x, off); s4.y += __shfl_xor(s4.y, off);
            s4.z += __shfl_xor(s4.z, off); s4.w += __shfl_xor(s4.w, off);
        }
        const float i0 = 1.f / (s4.x + 1e-16f), i1 = 1.f / (s4.y + 1e-16f);
        const float i2 = 1.f / (s4.z + 1e-16f), i3 = 1.f / (s4.w + 1e-16f);

        for (int c0 = start; c0 < end; c0 += 64) {
            const int nc = min(64, end - c0);
            const int j = c0 + lane;
            if (lane < nc) {
                float4 ex = *(const float4*)&alpha_perm[(size_t)j * 4];
                float4 al;
                al.x = ex.x * i0; al.y = ex.y * i1; al.z = ex.z * i2; al.w = ex.w * i3;
                *(float4*)&alpha_out[(size_t)eidp[j] * 4] = al;
                *(float4*)&alds[wid][lane][0] = al;
            }
            const int sjf = (lane < nc) ? src_perm[j] : 0;
            const float ajf = (lane < nc) ? attr_perm[j] : 0.f;
            int t = 0;
            for (; t + 1 < nc; t += 2) {
                const int s0 = __shfl(sjf, t), s1 = __shfl(sjf, t + 1);
                const float a0 = __shfl(ajf, t), a1 = __shfl(ajf, t + 1);
                const float w0 = alds[wid][t][h];
                const float w1 = alds[wid][t + 1][h];
                const unsigned u0 = vb[(size_t)s0 * 64 + lane];
                const unsigned u1 = vb[(size_t)s1 * 64 + lane];
                acc0 += w0 * (blo(u0) + a0 * we0 + be0) + w1 * (blo(u1) + a1 * we0 + be0);
                acc1 += w0 * (bhi(u0) + a0 * we1 + be1) + w1 * (bhi(u1) + a1 * we1 + be1);
            }
            if (t < nc) {
                const int s0 = __shfl(sjf, t);
                const float a0 = __shfl(ajf, t);
                const float w0 = alds[wid][t][h];
                const unsigned u0 = vb[(size_t)s0 * 64 + lane];
                acc0 += w0 * (blo(u0) + a0 * we0 + be0);
                acc1 += w0 * (bhi(u0) + a0 * we1 + be1);
            }
        }
    }

    // publish local stats (fast path); garbage for others is never used
    if (lane == 0) {
        cmb[wid][0] = m_w.x; cmb[wid][1] = m_w.y;
        cmb[wid][2] = m_w.z; cmb[wid][3] = m_w.w;
        cmb[wid][4] = s_w.x; cmb[wid][5] = s_w.y;
        cmb[wid][6] = s_w.z; cmb[wid][7] = s_w.w;
    }
    __syncthreads();

    if (live && deg > 0 && fast) {
        const int pw = wid ^ 1;
        const float4 m_p = make_float4(cmb[pw][0], cmb[pw][1], cmb[pw][2], cmb[pw][3]);
        const float4 s_p = make_float4(cmb[pw][4], cmb[pw][5], cmb[pw][6], cmb[pw][7]);
        float4 M;
        M.x = fmaxf(m_w.x, m_p.x); M.y = fmaxf(m_w.y, m_p.y);
        M.z = fmaxf(m_w.z, m_p.z); M.w = fmaxf(m_w.w, m_p.w);
        float4 rs, rp;
        rs.x = __expf(m_w.x - M.x); rp.x = __expf(m_p.x - M.x);
        rs.y = __expf(m_w.y - M.y); rp.y = __expf(m_p.y - M.y);
        rs.z = __expf(m_w.z - M.z); rp.z = __expf(m_p.z - M.z);
        rs.w = __expf(m_w.w - M.w); rp.w = __expf(m_p.w - M.w);
        float4 f;
        f.x = rs.x / (rs.x * s_w.x + rp.x * s_p.x + 1e-16f);
        f.y = rs.y / (rs.y * s_w.y + rp.y * s_p.y + 1e-16f);
        f.z = rs.z / (rs.z * s_w.z + rp.z * s_p.z + 1e-16f);
        f.w = rs.w / (rs.w * s_w.w + rp.w * s_p.w + 1e-16f);

        float4 al;
        al.x = evr.x * f.x; al.y = evr.y * f.y;
        al.z = evr.z * f.z; al.w = evr.w * f.w;
        if (valid) *(float4*)&alpha_out[(size_t)eidp[cstart + lane] * 4] = al;
        *(float4*)&alds[wid][lane][0] = al;

        // pass C over chunk
        int t = 0;
        for (; t + 3 < cdeg; t += 4) {
            const int s0 = __shfl(sj, t), s1 = __shfl(sj, t + 1);
            const int s2 = __shfl(sj, t + 2), s3 = __shfl(sj, t + 3);
            const float a0 = __shfl(aj, t), a1 = __shfl(aj, t + 1);
            const float a2 = __shfl(aj, t + 2), a3 = __shfl(aj, t + 3);
            const float w0 = alds[wid][t + 0][h];
            const float w1 = alds[wid][t + 1][h];
            const float w2 = alds[wid][t + 2][h];
            const float w3 = alds[wid][t + 3][h];
            const unsigned u0 = vb[(size_t)s0 * 64 + lane];
            const unsigned u1 = vb[(size_t)s1 * 64 + lane];
            const unsigned u2 = vb[(size_t)s2 * 64 + lane];
            const unsigned u3 = vb[(size_t)s3 * 64 + lane];
            acc0 += w0 * blo(u0) + w1 * blo(u1) + w2 * blo(u2) + w3 * blo(u3);
            acc1 += w0 * bhi(u0) + w1 * bhi(u1) + w2 * bhi(u2) + w3 * bhi(u3);
            sa += w0 * a0 + w1 * a1 + w2 * a2 + w3 * a3;
        }
        for (; t < cdeg; ++t) {
            const int s0 = __shfl(sj, t);
            const float a0 = __shfl(aj, t);
            const float w0 = alds[wid][t][h];
            const unsigned u0 = vb[(size_t)s0 * 64 + lane];
            acc0 += w0 * blo(u0);
            acc1 += w0 * bhi(u0);
            sa += w0 * a0;
        }
        acc0 += sa * we0;
        acc1 += sa * we1;
    }

    if (part == 1) {
        accb[nslot][lane][0] = acc0;
        accb[nslot][lane][1] = acc1;
    }
    __syncthreads();

    if (part == 0 && live) {
        acc0 += accb[nslot][lane][0];
        acc1 += accb[nslot][lane][1];
        float2 o = *(const float2*)&skip[(size_t)node * 128 + 2 * lane];
        if (deg > 0) {
            o.x += acc0; o.y += acc1;
            if (fast) { o.x += be0; o.y += be1; }
        }
        if (do_ln) {
            float s = o.x + o.y;
#pragma unroll
            for (int off = 1; off < 64; off <<= 1) s += __shfl_xor(s, off);
            const float mu = s * (1.f / 128.f);
            const float d0 = o.x - mu, d1 = o.y - mu;
            float vs = d0 * d0 + d1 * d1;
#pragma unroll
            for (int off = 1; off < 64; off <<= 1) vs += __shfl_xor(vs, off);
            const float inv = rsqrtf(vs * (1.f / 128.f) + 1e-5f);
            const float2 gv = *(const float2*)&lng[2 * lane];
            const float2 bv2 = *(const float2*)&lnb[2 * lane];
            const float n0 = fmaxf(d0 * inv * gv.x + bv2.x, 0.f);
            const float n1 = fmaxf(d1 * inv * gv.y + bv2.y, 0.f);
            hbout[(size_t)node * 64 + lane] = pack_bf16_rne(n0, n1);
        } else {
            *(float2*)&zout[(size_t)node * 128 + 2 * lane] = o;
        }
    }
}

// pool: one block per 32 rows, 128 threads (one per column); batch sorted
__global__ __launch_bounds__(128) void pool_kernel(const float* __restrict__ z,
                                                   const int* __restrict__ batch,
                                                   float* __restrict__ pool,
                                                   int* __restrict__ gcnt, int n) {
    const int c = threadIdx.x;
    const int row0 = blockIdx.x * 32;
    if (row0 >= n) return;
    const int rend = min(row0 + 32, n);
    int cur = batch[row0];
    float acc = 0.f;
    int run = 0;
    for (int r = row0; r < rend; ++r) {
        const int g = batch[r];
        if (g != cur) {
            atomicAdd(&pool[cur * 128 + c], acc);
            if (c == 0) atomicAdd(&gcnt[cur], run);
            acc = 0.f; run = 0; cur = g;
        }
        acc += z[(size_t)r * 128 + c];
        ++run;
    }
    atomicAdd(&pool[cur * 128 + c], acc);
    if (c == 0) atomicAdd(&gcnt[cur], run);
}

__global__ __launch_bounds__(128) void classifier_kernel(
    const float* __restrict__ pool, const int* __restrict__ gcnt,
    const int* __restrict__ batch,
    const float* __restrict__ fc1_w, const float* __restrict__ fc1_b,
    const float* __restrict__ cg, const float* __restrict__ cbv,
    const float* __restrict__ fc2_w, const float* __restrict__ fc2_b,
    float* __restrict__ zsel, float* __restrict__ probs) {
    __shared__ float zp[8][128];
    __shared__ float hc[8][128];
    __shared__ float red[2];
    __shared__ float lgt[8][10];
    const int c = threadIdx.x;
    const int lane = c & 63, wid = c >> 6;
#pragma unroll
    for (int g = 0; g < 8; ++g)
        zp[g][c] = pool[g * 128 + c] / fmaxf((float)gcnt[g], 1.f);
    __syncthreads();
    zsel[c] = zp[batch[0]][c];

    float acc[8];
#pragma unroll
    for (int g = 0; g < 8; ++g) acc[g] = fc1_b[c];
    for (int k = 0; k < 128; ++k) {
        const float w = fc1_w[k * 128 + c];
#pragma unroll
        for (int g = 0; g < 8; ++g) acc[g] += zp[g][k] * w;
    }
#pragma unroll
    for (int g = 0; g < 8; ++g) {
        float s = acc[g];
        for (int off = 1; off < 64; off <<= 1) s += __shfl_xor(s, off);
        if (lane == 0) red[wid] = s;
        __syncthreads();
        const float mu = (red[0] + red[1]) * (1.f / 128.f);
        __syncthreads();
        const float d = acc[g] - mu;
        float s2 = d * d;
        for (int off = 1; off < 64; off <<= 1) s2 += __shfl_xor(s2, off);
        if (lane == 0) red[wid] = s2;
        __syncthreads();
        const float var = (red[0] + red[1]) * (1.f / 128.f);
        __syncthreads();
        hc[g][c] = fmaxf(d * rsqrtf(var + 1e-5f) * cg[c] + cbv[c], 0.f);
    }
    __syncthreads();
    if (c < 80) {
        const int g = c / 10, j = c - g * 10;
        float s = fc2_b[j];
        for (int k = 0; k < 128; ++k) s += hc[g][k] * fc2_w[k * 10 + j];
        lgt[g][j] = s;
    }
    __syncthreads();
    if (c < 8) {
        float mx = -1e30f;
#pragma unroll
        for (int j = 0; j < 10; ++j) mx = fmaxf(mx, lgt[c][j]);
        float ex[10];
        float sum = 0.f;
#pragma unroll
        for (int j = 0; j < 10; ++j) { ex[j] = expf(lgt[c][j] - mx); sum += ex[j]; }
#pragma unroll
        for (int j = 0; j < 10; ++j) probs[c * 10 + j] = ex[j] / sum;
    }
}

// ---------------------------------------------------------------------------

extern "C" void kernel_launch(void* const* d_in, const int* in_sizes, int n_in,
                              void* d_out, int out_size, void* d_ws, size_t ws_size,
                              hipStream_t stream) {
    const float* x = (const float*)d_in[0];
    const int* edge_index = (const int*)d_in[1];
    const float* attr = (const float*)d_in[2];
    const int* batch = (const int*)d_in[3];
    const int N = in_sizes[0] / 128;
    const int E = in_sizes[2];
    const int* src = edge_index;
    const int* dst = edge_index + E;

    const float *Wq[3], *Wk[3], *Wv[3], *We[3], *Ws[3];
    const float *bq[3], *bk[3], *bv[3], *be[3], *bs[3];
    int idx = 4;
    for (int l = 0; l < 3; ++l) {
        Wq[l] = (const float*)d_in[idx++];
        Wk[l] = (const float*)d_in[idx++];
        Wv[l] = (const float*)d_in[idx++];
        We[l] = (const float*)d_in[idx++];
        Ws[l] = (const float*)d_in[idx++];
        bq[l] = (const float*)d_in[idx++];
        bk[l] = (const float*)d_in[idx++];
        bv[l] = (const float*)d_in[idx++];
        be[l] = (const float*)d_in[idx++];
        bs[l] = (const float*)d_in[idx++];
    }
    const float* ln_g[2] = {(const float*)d_in[34], (const float*)d_in[36]};
    const float* ln_b[2] = {(const float*)d_in[35], (const float*)d_in[37]};
    const float* fc1_w = (const float*)d_in[38];
    const float* fc1_b = (const float*)d_in[39];
    const float* cln_g = (const float*)d_in[40];
    const float* cln_b = (const float*)d_in[41];
    const float* fc2_w = (const float*)d_in[42];
    const float* fc2_b = (const float*)d_in[43];
    const int C = in_sizes[43];

    float* out = (float*)d_out;
    float* z_out = out;
    float* zsel_out = out + (size_t)N * 128;
    float* probs_out = zsel_out + 128;
    const int GC = out_size - N * 128 - 128 - 3 * E * 4;
    const int G = GC / C;  // = 8
    float* alpha_out[3];
    alpha_out[0] = probs_out + GC;
    alpha_out[1] = alpha_out[0] + (size_t)E * 4;
    alpha_out[2] = alpha_out[1] + (size_t)E * 4;

    // workspace layout
    char* p = (char*)d_ws;
    auto alloc = [&](size_t bytes) {
        void* r = (void*)p;
        p += (bytes + 255) & ~(size_t)255;
        return r;
    };
    float* qb = (float*)alloc((size_t)N * 128 * 4);
    unsigned* kb = (unsigned*)alloc((size_t)N * 64 * 4);
    unsigned* vb = (unsigned*)alloc((size_t)N * 64 * 4);
    float* hA = (float*)alloc((size_t)N * 128 * 4);       // skip buffer (layers 0,1)
    unsigned* xb = (unsigned*)alloc((size_t)N * 64 * 4);  // bf16 x
    unsigned* hb = (unsigned*)alloc((size_t)N * 64 * 4);  // bf16 LN output
    unsigned* wt = (unsigned*)alloc((size_t)12 * 8192 * 4);
    int* counts = (int*)alloc((size_t)N * 4);
    int* rowptr = (int*)alloc((size_t)(N + 1) * 4);
    int* cnt2 = (int*)alloc((size_t)N * 4);
    int* bsum = (int*)alloc((size_t)1024 * 4);
    int* src_perm = (int*)alloc((size_t)E * 4);
    float* attr_perm = (float*)alloc((size_t)E * 4);
    int* eidp = (int*)alloc((size_t)E * 4);
    float* alpha_perm = (float*)alloc((size_t)E * 4 * 4);
    float* pool = (float*)alloc((size_t)G * 128 * 4);
    int* gcnt = (int*)alloc((size_t)G * 4);

    hipMemsetAsync(counts, 0, (size_t)N * 4, stream);
    hipMemsetAsync(cnt2, 0, (size_t)N * 4, stream);
    hipMemsetAsync(pool, 0, (size_t)G * 128 * 4, stream);
    hipMemsetAsync(gcnt, 0, (size_t)G * 4, stream);

    const int nb = (N + 255) / 256;  // <= 1024
    hist_kernel<<<(E + 255) / 256, 256, 0, stream>>>(dst, counts, E);
    blk_reduce_kernel<<<nb, 256, 0, stream>>>(counts, bsum, N);
    blk_scan_kernel<<<1, 1024, 0, stream>>>(bsum, nb);
    rowptr_fill_kernel<<<nb, 256, 0, stream>>>(counts, bsum, rowptr, N);
    fill_kernel<<<(E + 255) / 256, 256, 0, stream>>>(src, dst, attr, rowptr, cnt2,
                                                     src_perm, attr_perm, eidp, E);

    cvt_bf16_kernel<<<(N * 64 + 255) / 256, 256, 0, stream>>>(x, xb, N * 64);
    W12 ws;
    for (int l = 0; l < 3; ++l) {
        ws.p[l * 4 + 0] = Wq[l]; ws.p[l * 4 + 1] = Wk[l];
        ws.p[l * 4 + 2] = Wv[l]; ws.p[l * 4 + 3] = Ws[l];
    }
    prepack_all_kernel<<<dim3(32, 12), 256, 0, stream>>>(ws, wt);

    for (int l = 0; l < 3; ++l) {
        float* SKIP = (l < 2) ? hA : z_out;
        const unsigned short* Xin = (const unsigned short*)((l == 0) ? xb : hb);
        gemm_mfma_kernel<<<dim3((N + 63) / 64, 2), 256, 0, stream>>>(
            Xin, (const unsigned short*)(wt + (size_t)l * 4 * 8192),
            bq[l], bk[l], bv[l], bs[l],
            qb, (unsigned short*)kb, (unsigned short*)vb, SKIP, N);
        node_fused_kernel<<<(N + 1) / 2, 256, 0, stream>>>(
            qb, kb, vb, We[l], be[l], rowptr, src_perm, attr_perm, eidp,
            alpha_perm, alpha_out[l], SKIP, z_out, hb,
            (l < 2) ? ln_g[l] : ln_g[0], (l < 2) ? ln_b[l] : ln_b[0],
            (l < 2) ? 1 : 0, N);
    }

    pool_kernel<<<(N + 31) / 32, 128, 0, stream>>>(z_out, batch, pool, gcnt, N);
    classifier_kernel<<<1, 128, 0, stream>>>(pool, gcnt, batch, fc1_w, fc1_b,
                                             cln_g, cln_b, fc2_w, fc2_b,
                                             zsel_out, probs_out);
}

// Round 10
// 444.613 us; speedup vs baseline: 1.1928x; 1.1928x over previous
//
#include <hip/hip_runtime.h>

// ---------------------------------------------------------------------------
// GraphVAE (3x TransformerConv + LN/ReLU + mean-pool + classifier).
// Round 10: ONLINE-softmax single-gather node kernel (fused kv[N][128] u32
// buffer, one 512B row touch per edge, flash-style m/s/acc/sa rescale;
// pass C and the separate softmax reduce are gone). 1 wave/node.
// Paired MFMA GEMM (q,k | v,s) kept from r9 (saved ~12us).
// ---------------------------------------------------------------------------

typedef short short8v __attribute__((ext_vector_type(8)));
typedef float f32x4 __attribute__((ext_vector_type(4)));

__device__ __forceinline__ unsigned pack_bf16_rne(float a, float b) {
    unsigned ua = __float_as_uint(a);
    ua += 0x7fffu + ((ua >> 16) & 1u);
    unsigned ub = __float_as_uint(b);
    ub += 0x7fffu + ((ub >> 16) & 1u);
    return (ua >> 16) | (ub & 0xffff0000u);
}

__device__ __forceinline__ unsigned short bf16_rne1(float a) {
    unsigned u = __float_as_uint(a);
    u += 0x7fffu + ((u >> 16) & 1u);
    return (unsigned short)(u >> 16);
}

__device__ __forceinline__ float blo(unsigned u) { return __uint_as_float(u << 16); }
__device__ __forceinline__ float bhi(unsigned u) { return __uint_as_float(u & 0xffff0000u); }

__global__ __launch_bounds__(256) void hist_kernel(const int* __restrict__ dst,
                                                   int* __restrict__ cnt, int E) {
    int e = blockIdx.x * 256 + threadIdx.x;
    if (e < E) atomicAdd(&cnt[dst[e]], 1);
}

// ---- parallel scan: per-block reduce -> single-block scan -> fill ----
__global__ __launch_bounds__(256) void blk_reduce_kernel(const int* __restrict__ cnt,
                                                         int* __restrict__ bsum, int n) {
    __shared__ int ws[4];
    const int i = blockIdx.x * 256 + threadIdx.x;
    const int lane = threadIdx.x & 63, wid = threadIdx.x >> 6;
    int v = (i < n) ? cnt[i] : 0;
#pragma unroll
    for (int off = 1; off < 64; off <<= 1) v += __shfl_xor(v, off);
    if (lane == 0) ws[wid] = v;
    __syncthreads();
    if (threadIdx.x == 0) bsum[blockIdx.x] = ws[0] + ws[1] + ws[2] + ws[3];
}

__global__ __launch_bounds__(1024) void blk_scan_kernel(int* __restrict__ bsum, int nb) {
    __shared__ int wls[16];
    const int tid = threadIdx.x, lane = tid & 63, wid = tid >> 6;
    int v = (tid < nb) ? bsum[tid] : 0;
    int sc = v;
#pragma unroll
    for (int off = 1; off < 64; off <<= 1) {
        int t = __shfl_up(sc, off);
        if (lane >= off) sc += t;
    }
    if (lane == 63) wls[wid] = sc;
    __syncthreads();
    if (tid == 0) {
        int run = 0;
        for (int w = 0; w < 16; ++w) { int t = wls[w]; wls[w] = run; run += t; }
    }
    __syncthreads();
    if (tid < nb) bsum[tid] = wls[wid] + sc - v;  // exclusive
}

__global__ __launch_bounds__(256) void rowptr_fill_kernel(const int* __restrict__ cnt,
                                                          const int* __restrict__ boff,
                                                          int* __restrict__ rowptr, int n) {
    __shared__ int wls[4];
    const int i = blockIdx.x * 256 + threadIdx.x;
    const int lane = threadIdx.x & 63, wid = threadIdx.x >> 6;
    int v = (i < n) ? cnt[i] : 0;
    int sc = v;
#pragma unroll
    for (int off = 1; off < 64; off <<= 1) {
        int t = __shfl_up(sc, off);
        if (lane >= off) sc += t;
    }
    if (lane == 63) wls[wid] = sc;
    __syncthreads();
    int add = boff[blockIdx.x];
    for (int w = 0; w < wid; ++w) add += wls[w];
    if (i < n) rowptr[i + 1] = sc + add;
    if (i == 0) rowptr[0] = 0;
}

__global__ __launch_bounds__(256) void fill_kernel(const int* __restrict__ src,
                                                   const int* __restrict__ dst,
                                                   const float* __restrict__ attr,
                                                   const int* __restrict__ rowptr,
                                                   int* __restrict__ tmp,
                                                   int* __restrict__ src_perm,
                                                   float* __restrict__ attr_perm,
                                                   int* __restrict__ eidp, int E) {
    int e = blockIdx.x * 256 + threadIdx.x;
    if (e < E) {
        int d = dst[e];
        int p = atomicAdd(&tmp[d], 1);
        int pos = rowptr[d] + p;
        src_perm[pos] = src[e];
        attr_perm[pos] = attr[e];
        eidp[pos] = e;
    }
}

__global__ __launch_bounds__(256) void cvt_bf16_kernel(const float* __restrict__ in,
                                                       unsigned* __restrict__ outp, int n32) {
    int i = blockIdx.x * 256 + threadIdx.x;
    if (i < n32) {
        float2 v = *(const float2*)&in[(size_t)i * 2];
        outp[i] = pack_bf16_rne(v.x, v.y);
    }
}

struct W12 { const float* p[12]; };
__global__ __launch_bounds__(256) void prepack_all_kernel(W12 ws, unsigned* __restrict__ wt) {
    const int m = blockIdx.y;
    const float* W = ws.p[m];
    int idx = blockIdx.x * 256 + threadIdx.x;
    int c = idx >> 6;
    int kp = idx & 63;
    wt[(size_t)m * 8192 + (size_t)c * 64 + kp] =
        pack_bf16_rne(W[(size_t)(2 * kp) * 128 + c], W[(size_t)(2 * kp + 1) * 128 + c]);
}

// ---------------------------------------------------------------------------
// MFMA GEMM, 2 matrices per block: y=0 -> {q f32, k->kv[0:128)};
//                                  y=1 -> {v->kv[128:256), s f32}
// kvo is u16 base of kv[N][256] (u16 view of [N][128] u32).
// ---------------------------------------------------------------------------
__global__ __launch_bounds__(256) void gemm_mfma_kernel(
    const unsigned short* __restrict__ Xb, const unsigned short* __restrict__ wt,
    const float* __restrict__ bq, const float* __restrict__ bk,
    const float* __restrict__ bv, const float* __restrict__ bs,
    float* __restrict__ qo, unsigned short* __restrict__ kvo,
    float* __restrict__ so, int nrows) {
    const int lane = threadIdx.x & 63;
    const int w = threadIdx.x >> 6;
    const int pair = blockIdx.y;             // 0: q,k   1: v,s
    const int strip = blockIdx.x * 64 + w * 16;
    const int arow = strip + (lane & 15);
    const int arow_c = min(arow, nrows - 1);
    const int kblk = (lane >> 4) * 8;
    const unsigned short* WmA = wt + (size_t)(pair * 2) * 16384;      // q or v
    const unsigned short* WmB = wt + (size_t)(pair * 2 + 1) * 16384;  // k or s
    const float* biasA = (pair == 0) ? bq : bv;
    const float* biasB = (pair == 0) ? bk : bs;

    f32x4 accA[8], accB[8];
#pragma unroll
    for (int f = 0; f < 8; ++f) {
        accA[f] = (f32x4){0.f, 0.f, 0.f, 0.f};
        accB[f] = (f32x4){0.f, 0.f, 0.f, 0.f};
    }

#pragma unroll
    for (int ks = 0; ks < 4; ++ks) {
        const int k0 = ks * 32 + kblk;
        const short8v a = *(const short8v*)&Xb[(size_t)arow_c * 128 + k0];
#pragma unroll
        for (int f = 0; f < 8; ++f) {
            const size_t boff = (size_t)(f * 16 + (lane & 15)) * 128 + k0;
            const short8v b0 = *(const short8v*)&WmA[boff];
            const short8v b1 = *(const short8v*)&WmB[boff];
            accA[f] = __builtin_amdgcn_mfma_f32_16x16x32_bf16(a, b0, accA[f], 0, 0, 0);
            accB[f] = __builtin_amdgcn_mfma_f32_16x16x32_bf16(a, b1, accB[f], 0, 0, 0);
        }
    }

    const int r0 = strip + (lane >> 4) * 4;
#pragma unroll
    for (int f = 0; f < 8; ++f) {
        const int col = f * 16 + (lane & 15);
        const float bA = biasA[col];
        const float bB = biasB[col];
#pragma unroll
        for (int r = 0; r < 4; ++r) {
            int row = r0 + r;
            if (row < nrows) {
                if (pair == 0) {
                    qo[(size_t)row * 128 + col] = accA[f][r] + bA;
                    kvo[(size_t)row * 256 + col] = bf16_rne1(accB[f][r] + bB);       // k
                } else {
                    kvo[(size_t)row * 256 + 128 + col] = bf16_rne1(accA[f][r] + bA); // v
                    so[(size_t)row * 128 + col] = accB[f][r] + bB;
                }
            }
        }
    }
}

// ---------------------------------------------------------------------------
// Fused node kernel v4 (1 wave/node, 4 nodes/block): ONLINE softmax, single
// gather pass over fused kv rows. Per edge: gather k-half + v-half of the
// same 512B row, logit via 16-lane reduce, online update of (m, s, acc, sa).
// Logits stashed in alds; alpha = exp(p - m)/s written at the end.
// deg<=64 fast path; deg>64 fallback = old 3-pass. Epilogue: skip+be+LN/ReLU.
// Lane layout: lane l owns dims (2l, 2l+1); head h = l>>4.
// ---------------------------------------------------------------------------
__global__ __launch_bounds__(256) void node_fused_kernel(
    const float* __restrict__ qb, const unsigned* __restrict__ kv,
    const float* __restrict__ Wev, const float* __restrict__ bev,
    const int* __restrict__ rowptr, const int* __restrict__ src_perm,
    const float* __restrict__ attr_perm, const int* __restrict__ eidp,
    float* __restrict__ alpha_perm, float* __restrict__ alpha_out,
    const float* __restrict__ skip, float* __restrict__ zout,
    unsigned* __restrict__ hbout,
    const float* __restrict__ lng, const float* __restrict__ lnb,
    int do_ln, int n) {
    __shared__ float alds[4][64][4];
    const int wid = threadIdx.x >> 6;
    const int node = blockIdx.x * 4 + wid;
    const int lane = threadIdx.x & 63;
    if (node >= n) return;
    const int start = rowptr[node], end = rowptr[node + 1];
    const int deg = end - start;
    const int h = lane >> 4;
    const float we0 = Wev[2 * lane], we1 = Wev[2 * lane + 1];
    const float be0 = bev[2 * lane], be1 = bev[2 * lane + 1];
    const float2 qv = *(const float2*)&qb[(size_t)node * 128 + 2 * lane];
    const float scale = 0.17677669529663687f;  // 1/sqrt(32)
    const bool fastp = (deg <= 64);

    float acc0 = 0.f, acc1 = 0.f, sa = 0.f;

    if (deg > 0 && fastp) {
        // per-head q.we, q.be
        float pw = qv.x * we0 + qv.y * we1;
        float pb = qv.x * be0 + qv.y * be1;
#pragma unroll
        for (int off = 1; off < 16; off <<= 1) {
            pw += __shfl_xor(pw, off);
            pb += __shfl_xor(pb, off);
        }
        const bool valid = lane < deg;
        const int j = start + lane;
        const int sj = valid ? src_perm[j] : 0;
        const float aj = valid ? attr_perm[j] : 0.f;

        float m = -1e30f, s = 0.f;

        // single pass: gather kv row, logit, online update
        int t = 0;
        for (; t + 3 < deg; t += 4) {
            const int s0 = __shfl(sj, t), s1 = __shfl(sj, t + 1);
            const int s2 = __shfl(sj, t + 2), s3 = __shfl(sj, t + 3);
            const float a0 = __shfl(aj, t), a1 = __shfl(aj, t + 1);
            const float a2 = __shfl(aj, t + 2), a3 = __shfl(aj, t + 3);
            const unsigned uk0 = kv[(size_t)s0 * 128 + lane];
            const unsigned uv0 = kv[(size_t)s0 * 128 + 64 + lane];
            const unsigned uk1 = kv[(size_t)s1 * 128 + lane];
            const unsigned uv1 = kv[(size_t)s1 * 128 + 64 + lane];
            const unsigned uk2 = kv[(size_t)s2 * 128 + lane];
            const unsigned uv2 = kv[(size_t)s2 * 128 + 64 + lane];
            const unsigned uk3 = kv[(size_t)s3 * 128 + lane];
            const unsigned uv3 = kv[(size_t)s3 * 128 + 64 + lane];
            float p0 = qv.x * blo(uk0) + qv.y * bhi(uk0);
            float p1 = qv.x * blo(uk1) + qv.y * bhi(uk1);
            float p2 = qv.x * blo(uk2) + qv.y * bhi(uk2);
            float p3 = qv.x * blo(uk3) + qv.y * bhi(uk3);
#pragma unroll
            for (int off = 1; off < 16; off <<= 1) {
                p0 += __shfl_xor(p0, off); p1 += __shfl_xor(p1, off);
                p2 += __shfl_xor(p2, off); p3 += __shfl_xor(p3, off);
            }
            p0 = (p0 + a0 * pw + pb) * scale;
            p1 = (p1 + a1 * pw + pb) * scale;
            p2 = (p2 + a2 * pw + pb) * scale;
            p3 = (p3 + a3 * pw + pb) * scale;
            if ((lane & 15) == 0) {
                alds[wid][t + 0][h] = p0;
                alds[wid][t + 1][h] = p1;
                alds[wid][t + 2][h] = p2;
                alds[wid][t + 3][h] = p3;
            }
            // online updates (serial in t, cheap)
            {
                const float mn = fmaxf(m, p0);
                const float f = __expf(m - mn), w = __expf(p0 - mn);
                acc0 = acc0 * f + w * blo(uv0);
                acc1 = acc1 * f + w * bhi(uv0);
                s = s * f + w; sa = sa * f + w * a0; m = mn;
            }
            {
                const float mn = fmaxf(m, p1);
                const float f = __expf(m - mn), w = __expf(p1 - mn);
                acc0 = acc0 * f + w * blo(uv1);
                acc1 = acc1 * f + w * bhi(uv1);
                s = s * f + w; sa = sa * f + w * a1; m = mn;
            }
            {
                const float mn = fmaxf(m, p2);
                const float f = __expf(m - mn), w = __expf(p2 - mn);
                acc0 = acc0 * f + w * blo(uv2);
                acc1 = acc1 * f + w * bhi(uv2);
                s = s * f + w; sa = sa * f + w * a2; m = mn;
            }
            {
                const float mn = fmaxf(m, p3);
                const float f = __expf(m - mn), w = __expf(p3 - mn);
                acc0 = acc0 * f + w * blo(uv3);
                acc1 = acc1 * f + w * bhi(uv3);
                s = s * f + w; sa = sa * f + w * a3; m = mn;
            }
        }
        for (; t < deg; ++t) {
            const int s0 = __shfl(sj, t);
            const float a0 = __shfl(aj, t);
            const unsigned uk0 = kv[(size_t)s0 * 128 + lane];
            const unsigned uv0 = kv[(size_t)s0 * 128 + 64 + lane];
            float p0 = qv.x * blo(uk0) + qv.y * bhi(uk0);
#pragma unroll
            for (int off = 1; off < 16; off <<= 1) p0 += __shfl_xor(p0, off);
            p0 = (p0 + a0 * pw + pb) * scale;
            if ((lane & 15) == 0) alds[wid][t][h] = p0;
            const float mn = fmaxf(m, p0);
            const float f = __expf(m - mn), w = __expf(p0 - mn);
            acc0 = acc0 * f + w * blo(uv0);
            acc1 = acc1 * f + w * bhi(uv0);
            s = s * f + w; sa = sa * f + w * a0; m = mn;
        }

        // finalize: normalize accumulators; write alpha from stashed logits
        const float inv = 1.f / (s + 1e-16f);
        acc0 *= inv; acc1 *= inv; sa *= inv;

        const float m0 = __shfl(m, 0), m1 = __shfl(m, 16);
        const float m2 = __shfl(m, 32), m3 = __shfl(m, 48);
        const float i0 = __shfl(inv, 0), i1 = __shfl(inv, 16);
        const float i2 = __shfl(inv, 32), i3 = __shfl(inv, 48);
        if (valid) {
            const float4 lg = *(const float4*)&alds[wid][lane][0];
            float4 al;
            al.x = __expf(lg.x - m0) * i0;
            al.y = __expf(lg.y - m1) * i1;
            al.z = __expf(lg.z - m2) * i2;
            al.w = __expf(lg.w - m3) * i3;
            *(float4*)&alpha_out[(size_t)eidp[j] * 4] = al;
        }
        acc0 += sa * we0;
        acc1 += sa * we1;
    } else if (deg > 0) {
        // ---------------- fallback (deg > 64): 3-pass via alpha_perm ----------------
        float mh = -1e30f;
        for (int c0 = start; c0 < end; c0 += 64) {
            const int nc = min(64, end - c0);
            const int sjf = (lane < nc) ? src_perm[c0 + lane] : 0;
            const float ajf = (lane < nc) ? attr_perm[c0 + lane] : 0.f;
            int t = 0;
            for (; t + 1 < nc; t += 2) {
                const int s0 = __shfl(sjf, t), s1 = __shfl(sjf, t + 1);
                const float a0 = __shfl(ajf, t), a1 = __shfl(ajf, t + 1);
                const unsigned u0 = kv[(size_t)s0 * 128 + lane];
                const unsigned u1 = kv[(size_t)s1 * 128 + lane];
                float p0 = qv.x * (blo(u0) + a0 * we0 + be0) + qv.y * (bhi(u0) + a0 * we1 + be1);
                float p1 = qv.x * (blo(u1) + a1 * we0 + be0) + qv.y * (bhi(u1) + a1 * we1 + be1);
#pragma unroll
                for (int off = 1; off < 16; off <<= 1) {
                    p0 += __shfl_xor(p0, off);
                    p1 += __shfl_xor(p1, off);
                }
                p0 *= scale; p1 *= scale;
                mh = fmaxf(mh, fmaxf(p0, p1));
                if ((lane & 15) == 0) {
                    alpha_perm[(size_t)(c0 + t) * 4 + h] = p0;
                    alpha_perm[(size_t)(c0 + t + 1) * 4 + h] = p1;
                }
            }
            if (t < nc) {
                const int s0 = __shfl(sjf, t);
                const float a0 = __shfl(ajf, t);
                const unsigned u0 = kv[(size_t)s0 * 128 + lane];
                float p0 = qv.x * (blo(u0) + a0 * we0 + be0) + qv.y * (bhi(u0) + a0 * we1 + be1);
#pragma unroll
                for (int off = 1; off < 16; off <<= 1) p0 += __shfl_xor(p0, off);
                p0 *= scale;
                mh = fmaxf(mh, p0);
                if ((lane & 15) == 0) alpha_perm[(size_t)(c0 + t) * 4 + h] = p0;
            }
        }
        const float m0 = __shfl(mh, 0), m1 = __shfl(mh, 16);
        const float m2 = __shfl(mh, 32), m3 = __shfl(mh, 48);

        float4 s4 = make_float4(0.f, 0.f, 0.f, 0.f);
        for (int c0 = start; c0 < end; c0 += 64) {
            const int j = c0 + lane;
            if (j < end) {
                float4 lg = *(const float4*)&alpha_perm[(size_t)j * 4];
                lg.x = __expf(lg.x - m0); lg.y = __expf(lg.y - m1);
                lg.z = __expf(lg.z - m2); lg.w = __expf(lg.w - m3);
                *(float4*)&alpha_perm[(size_t)j * 4] = lg;
                s4.x += lg.x; s4.y += lg.y; s4.z += lg.z; s4.w += lg.w;
            }
        }
#pragma unroll
        for (int off = 1; off < 64; off <<= 1) {
            s4.x += __shfl_xor(s4.x, off); s4.y += __shfl_xor(s4.y, off);
            s4.z += __shfl_xor(s4.z, off); s4.w += __shfl_xor(s4.w, off);
        }
        const float i0 = 1.f / (s4.x + 1e-16f), i1 = 1.f / (s4.y + 1e-16f);
        const float i2 = 1.f / (s4.z + 1e-16f), i3 = 1.f / (s4.w + 1e-16f);

        for (int c0 = start; c0 < end; c0 += 64) {
            const int nc = min(64, end - c0);
            const int j = c0 + lane;
            if (lane < nc) {
                float4 ex = *(const float4*)&alpha_perm[(size_t)j * 4];
                float4 al;
                al.x = ex.x * i0; al.y = ex.y * i1; al.z = ex.z * i2; al.w = ex.w * i3;
                *(float4*)&alpha_out[(size_t)eidp[j] * 4] = al;
                *(float4*)&alds[wid][lane][0] = al;
            }
            const int sjf = (lane < nc) ? src_perm[j] : 0;
            const float ajf = (lane < nc) ? attr_perm[j] : 0.f;
            int t = 0;
            for (; t + 1 < nc; t += 2) {
                const int s0 = __shfl(sjf, t), s1 = __shfl(sjf, t + 1);
                const float a0 = __shfl(ajf, t), a1 = __shfl(ajf, t + 1);
                const float w0 = alds[wid][t][h];
                const float w1 = alds[wid][t + 1][h];
                const unsigned u0 = kv[(size_t)s0 * 128 + 64 + lane];
                const unsigned u1 = kv[(size_t)s1 * 128 + 64 + lane];
                acc0 += w0 * (blo(u0) + a0 * we0 + be0) + w1 * (blo(u1) + a1 * we0 + be0);
                acc1 += w0 * (bhi(u0) + a0 * we1 + be1) + w1 * (bhi(u1) + a1 * we1 + be1);
            }
            if (t < nc) {
                const int s0 = __shfl(sjf, t);
                const float a0 = __shfl(ajf, t);
                const float w0 = alds[wid][t][h];
                const unsigned u0 = kv[(size_t)s0 * 128 + 64 + lane];
                acc0 += w0 * (blo(u0) + a0 * we0 + be0);
                acc1 += w0 * (bhi(u0) + a0 * we1 + be1);
            }
        }
    }

    // ---- epilogue: skip + aggregate (+be for fast path), LN/ReLU ----
    float2 o = *(const float2*)&skip[(size_t)node * 128 + 2 * lane];
    if (deg > 0) {
        o.x += acc0; o.y += acc1;
        if (fastp) { o.x += be0; o.y += be1; }
    }
    if (do_ln) {
        float s = o.x + o.y;
#pragma unroll
        for (int off = 1; off < 64; off <<= 1) s += __shfl_xor(s, off);
        const float mu = s * (1.f / 128.f);
        const float d0 = o.x - mu, d1 = o.y - mu;
        float vs = d0 * d0 + d1 * d1;
#pragma unroll
        for (int off = 1; off < 64; off <<= 1) vs += __shfl_xor(vs, off);
        const float inv = rsqrtf(vs * (1.f / 128.f) + 1e-5f);
        const float2 gv = *(const float2*)&lng[2 * lane];
        const float2 bv2 = *(const float2*)&lnb[2 * lane];
        const float n0 = fmaxf(d0 * inv * gv.x + bv2.x, 0.f);
        const float n1 = fmaxf(d1 * inv * gv.y + bv2.y, 0.f);
        hbout[(size_t)node * 64 + lane] = pack_bf16_rne(n0, n1);
    } else {
        *(float2*)&zout[(size_t)node * 128 + 2 * lane] = o;
    }
}

// pool: one block per 32 rows, 128 threads (one per column); batch sorted
__global__ __launch_bounds__(128) void pool_kernel(const float* __restrict__ z,
                                                   const int* __restrict__ batch,
                                                   float* __restrict__ pool,
                                                   int* __restrict__ gcnt, int n) {
    const int c = threadIdx.x;
    const int row0 = blockIdx.x * 32;
    if (row0 >= n) return;
    const int rend = min(row0 + 32, n);
    int cur = batch[row0];
    float acc = 0.f;
    int run = 0;
    for (int r = row0; r < rend; ++r) {
        const int g = batch[r];
        if (g != cur) {
            atomicAdd(&pool[cur * 128 + c], acc);
            if (c == 0) atomicAdd(&gcnt[cur], run);
            acc = 0.f; run = 0; cur = g;
        }
        acc += z[(size_t)r * 128 + c];
        ++run;
    }
    atomicAdd(&pool[cur * 128 + c], acc);
    if (c == 0) atomicAdd(&gcnt[cur], run);
}

__global__ __launch_bounds__(128) void classifier_kernel(
    const float* __restrict__ pool, const int* __restrict__ gcnt,
    const int* __restrict__ batch,
    const float* __restrict__ fc1_w, const float* __restrict__ fc1_b,
    const float* __restrict__ cg, const float* __restrict__ cbv,
    const float* __restrict__ fc2_w, const float* __restrict__ fc2_b,
    float* __restrict__ zsel, float* __restrict__ probs) {
    __shared__ float zp[8][128];
    __shared__ float hc[8][128];
    __shared__ float red[2];
    __shared__ float lgt[8][10];
    const int c = threadIdx.x;
    const int lane = c & 63, wid = c >> 6;
#pragma unroll
    for (int g = 0; g < 8; ++g)
        zp[g][c] = pool[g * 128 + c] / fmaxf((float)gcnt[g], 1.f);
    __syncthreads();
    zsel[c] = zp[batch[0]][c];

    float acc[8];
#pragma unroll
    for (int g = 0; g < 8; ++g) acc[g] = fc1_b[c];
    for (int k = 0; k < 128; ++k) {
        const float w = fc1_w[k * 128 + c];
#pragma unroll
        for (int g = 0; g < 8; ++g) acc[g] += zp[g][k] * w;
    }
#pragma unroll
    for (int g = 0; g < 8; ++g) {
        float s = acc[g];
        for (int off = 1; off < 64; off <<= 1) s += __shfl_xor(s, off);
        if (lane == 0) red[wid] = s;
        __syncthreads();
        const float mu = (red[0] + red[1]) * (1.f / 128.f);
        __syncthreads();
        const float d = acc[g] - mu;
        float s2 = d * d;
        for (int off = 1; off < 64; off <<= 1) s2 += __shfl_xor(s2, off);
        if (lane == 0) red[wid] = s2;
        __syncthreads();
        const float var = (red[0] + red[1]) * (1.f / 128.f);
        __syncthreads();
        hc[g][c] = fmaxf(d * rsqrtf(var + 1e-5f) * cg[c] + cbv[c], 0.f);
    }
    __syncthreads();
    if (c < 80) {
        const int g = c / 10, j = c - g * 10;
        float s = fc2_b[j];
        for (int k = 0; k < 128; ++k) s += hc[g][k] * fc2_w[k * 10 + j];
        lgt[g][j] = s;
    }
    __syncthreads();
    if (c < 8) {
        float mx = -1e30f;
#pragma unroll
        for (int j = 0; j < 10; ++j) mx = fmaxf(mx, lgt[c][j]);
        float ex[10];
        float sum = 0.f;
#pragma unroll
        for (int j = 0; j < 10; ++j) { ex[j] = expf(lgt[c][j] - mx); sum += ex[j]; }
#pragma unroll
        for (int j = 0; j < 10; ++j) probs[c * 10 + j] = ex[j] / sum;
    }
}

// ---------------------------------------------------------------------------

extern "C" void kernel_launch(void* const* d_in, const int* in_sizes, int n_in,
                              void* d_out, int out_size, void* d_ws, size_t ws_size,
                              hipStream_t stream) {
    const float* x = (const float*)d_in[0];
    const int* edge_index = (const int*)d_in[1];
    const float* attr = (const float*)d_in[2];
    const int* batch = (const int*)d_in[3];
    const int N = in_sizes[0] / 128;
    const int E = in_sizes[2];
    const int* src = edge_index;
    const int* dst = edge_index + E;

    const float *Wq[3], *Wk[3], *Wv[3], *We[3], *Ws[3];
    const float *bq[3], *bk[3], *bv[3], *be[3], *bs[3];
    int idx = 4;
    for (int l = 0; l < 3; ++l) {
        Wq[l] = (const float*)d_in[idx++];
        Wk[l] = (const float*)d_in[idx++];
        Wv[l] = (const float*)d_in[idx++];
        We[l] = (const float*)d_in[idx++];
        Ws[l] = (const float*)d_in[idx++];
        bq[l] = (const float*)d_in[idx++];
        bk[l] = (const float*)d_in[idx++];
        bv[l] = (const float*)d_in[idx++];
        be[l] = (const float*)d_in[idx++];
        bs[l] = (const float*)d_in[idx++];
    }
    const float* ln_g[2] = {(const float*)d_in[34], (const float*)d_in[36]};
    const float* ln_b[2] = {(const float*)d_in[35], (const float*)d_in[37]};
    const float* fc1_w = (const float*)d_in[38];
    const float* fc1_b = (const float*)d_in[39];
    const float* cln_g = (const float*)d_in[40];
    const float* cln_b = (const float*)d_in[41];
    const float* fc2_w = (const float*)d_in[42];
    const float* fc2_b = (const float*)d_in[43];
    const int C = in_sizes[43];

    float* out = (float*)d_out;
    float* z_out = out;
    float* zsel_out = out + (size_t)N * 128;
    float* probs_out = zsel_out + 128;
    const int GC = out_size - N * 128 - 128 - 3 * E * 4;
    const int G = GC / C;  // = 8
    float* alpha_out[3];
    alpha_out[0] = probs_out + GC;
    alpha_out[1] = alpha_out[0] + (size_t)E * 4;
    alpha_out[2] = alpha_out[1] + (size_t)E * 4;

    // workspace layout
    char* p = (char*)d_ws;
    auto alloc = [&](size_t bytes) {
        void* r = (void*)p;
        p += (bytes + 255) & ~(size_t)255;
        return r;
    };
    float* qb = (float*)alloc((size_t)N * 128 * 4);
    unsigned* kv = (unsigned*)alloc((size_t)N * 128 * 4);  // fused k|v bf16 rows
    float* hA = (float*)alloc((size_t)N * 128 * 4);        // skip buffer (layers 0,1)
    unsigned* xb = (unsigned*)alloc((size_t)N * 64 * 4);   // bf16 x
    unsigned* hb = (unsigned*)alloc((size_t)N * 64 * 4);   // bf16 LN output
    unsigned* wt = (unsigned*)alloc((size_t)12 * 8192 * 4);
    int* counts = (int*)alloc((size_t)N * 4);
    int* rowptr = (int*)alloc((size_t)(N + 1) * 4);
    int* cnt2 = (int*)alloc((size_t)N * 4);
    int* bsum = (int*)alloc((size_t)1024 * 4);
    int* src_perm = (int*)alloc((size_t)E * 4);
    float* attr_perm = (float*)alloc((size_t)E * 4);
    int* eidp = (int*)alloc((size_t)E * 4);
    float* alpha_perm = (float*)alloc((size_t)E * 4 * 4);
    float* pool = (float*)alloc((size_t)G * 128 * 4);
    int* gcnt = (int*)alloc((size_t)G * 4);

    hipMemsetAsync(counts, 0, (size_t)N * 4, stream);
    hipMemsetAsync(cnt2, 0, (size_t)N * 4, stream);
    hipMemsetAsync(pool, 0, (size_t)G * 128 * 4, stream);
    hipMemsetAsync(gcnt, 0, (size_t)G * 4, stream);

    const int nb = (N + 255) / 256;  // <= 1024
    hist_kernel<<<(E + 255) / 256, 256, 0, stream>>>(dst, counts, E);
    blk_reduce_kernel<<<nb, 256, 0, stream>>>(counts, bsum, N);
    blk_scan_kernel<<<1, 1024, 0, stream>>>(bsum, nb);
    rowptr_fill_kernel<<<nb, 256, 0, stream>>>(counts, bsum, rowptr, N);
    fill_kernel<<<(E + 255) / 256, 256, 0, stream>>>(src, dst, attr, rowptr, cnt2,
                                                     src_perm, attr_perm, eidp, E);

    cvt_bf16_kernel<<<(N * 64 + 255) / 256, 256, 0, stream>>>(x, xb, N * 64);
    W12 ws;
    for (int l = 0; l < 3; ++l) {
        ws.p[l * 4 + 0] = Wq[l]; ws.p[l * 4 + 1] = Wk[l];
        ws.p[l * 4 + 2] = Wv[l]; ws.p[l * 4 + 3] = Ws[l];
    }
    prepack_all_kernel<<<dim3(32, 12), 256, 0, stream>>>(ws, wt);

    for (int l = 0; l < 3; ++l) {
        float* SKIP = (l < 2) ? hA : z_out;
        const unsigned short* Xin = (const unsigned short*)((l == 0) ? xb : hb);
        gemm_mfma_kernel<<<dim3((N + 63) / 64, 2), 256, 0, stream>>>(
            Xin, (const unsigned short*)(wt + (size_t)l * 4 * 8192),
            bq[l], bk[l], bv[l], bs[l],
            qb, (unsigned short*)kv, SKIP, N);
        node_fused_kernel<<<(N + 3) / 4, 256, 0, stream>>>(
            qb, kv, We[l], be[l], rowptr, src_perm, attr_perm, eidp,
            alpha_perm, alpha_out[l], SKIP, z_out, hb,
            (l < 2) ? ln_g[l] : ln_g[0], (l < 2) ? ln_b[l] : ln_b[0],
            (l < 2) ? 1 : 0, N);
    }

    pool_kernel<<<(N + 31) / 32, 128, 0, stream>>>(z_out, batch, pool, gcnt, N);
    classifier_kernel<<<1, 128, 0, stream>>>(pool, gcnt, batch, fc1_w, fc1_b,
                                             cln_g, cln_b, fc2_w, fc2_b,
                                             zsel_out, probs_out);
}